// Round 12
// baseline (199.247 us; speedup 1.0000x reference)
//
#include <hip/hip_runtime.h>
#include <hip/hip_fp16.h>
#include <cstdint>

#define N_NODES 50000
#define N_EDGES 800000
#define N_FEAT 256
#define HIDDEN 128
#define N_CLASSES 40
#define NBUCKET 196         // dst >> 8
#define EPB 3125            // edges per partition block (256 * 3125 = 800000)
#define BCAP 8192           // bucket capacity in ebuf (max count ~4400)
#define ROWS_PAD 50048      // 782 * 64
#define H2S 64              // h2 row stride (halves) = 128 B aligned

typedef _Float16 half8 __attribute__((ext_vector_type(8)));
typedef __fp16 fp16x2 __attribute__((ext_vector_type(2)));
typedef __attribute__((ext_vector_type(4))) float f32x4;

__device__ inline ushort f2h(float f) {
    return __half_as_ushort(__float2half_rn(f));
}
__device__ inline __half2 u2h2(uint u) {
    union { uint u; __half2 h; } v; v.u = u; return v.h;
}

// ---------------- 1) partition edges into fixed-capacity buckets + W1/W2 repack ----------------
// cursor[196] pre-zeroed by hipMemsetAsync; ends holding per-bucket edge counts.

__global__ __launch_bounds__(256) void partition_repack(
        const int* __restrict__ src, const int* __restrict__ dst,
        int* __restrict__ cursor, uint* __restrict__ ebuf,
        const float* __restrict__ W1, ushort* __restrict__ Bp1,
        const float* __restrict__ W2, ushort* __restrict__ Bp2) {
    __shared__ int h[NBUCKET];
    __shared__ int base[NBUCKET];
    __shared__ int cur[NBUCKET];
    int blk = blockIdx.x, t = threadIdx.x;
    int gid = blk * 256 + t;
    if (gid < 32768) {       // W1 repack into MFMA B-frag order (f16)
        int j = gid & 7, lane = (gid >> 3) & 63, kt = (gid >> 9) & 7, nt = gid >> 12;
        int k = kt * 32 + (lane >> 4) * 8 + j;
        int n = nt * 16 + (lane & 15);
        Bp1[gid] = f2h(W1[k * HIDDEN + n]);
    } else if (gid < 32768 + 6144) {   // W2 repack (3 nt * 4 kt * 64 * 8)
        int i2 = gid - 32768;
        int j = i2 & 7, lane = (i2 >> 3) & 63, kt = (i2 >> 9) & 3, nt = i2 >> 11;
        int k = kt * 32 + (lane >> 4) * 8 + j;
        int n = nt * 16 + (lane & 15);
        Bp2[i2] = (n < N_CLASSES) ? f2h(W2[k * N_CLASSES + n]) : (ushort)0;
    }
    if (t < NBUCKET) { h[t] = 0; cur[t] = 0; }
    __syncthreads();
    int eb = blk * EPB;
    for (int i = t; i < EPB; i += 256)
        atomicAdd(&h[dst[eb + i] >> 8], 1);
    __syncthreads();
    if (t < NBUCKET)
        base[t] = (h[t] > 0) ? atomicAdd(&cursor[t], h[t]) : 0;
    __syncthreads();
    for (int i = t; i < EPB; i += 256) {
        int d = dst[eb + i], sv = src[eb + i];
        int bk = d >> 8;
        int p = base[bk] + atomicAdd(&cur[bk], 1);
        ebuf[bk * BCAP + p] = ((uint)d << 16) | (uint)sv;
    }
}

// ---------------- 2) per-bucket: degree + dinv + rowptr + CSR fill ----------------

__global__ __launch_bounds__(256) void bucket_csr(
        const uint* __restrict__ ebuf, const int* __restrict__ cursor,
        int* __restrict__ deg, float* __restrict__ dinv,
        int* __restrict__ rowptr, int* __restrict__ esrc) {
    __shared__ int s[256];
    __shared__ int cnt[256];
    __shared__ int exc[256];
    __shared__ int cur[256];
    int b = blockIdx.x, t = threadIdx.x;
    s[t] = (t < NBUCKET) ? cursor[t] : 0;
    __syncthreads();
    for (int off = 1; off < 256; off <<= 1) {
        int t2 = 0;
        if (t >= off) t2 = s[t - off];
        __syncthreads();
        s[t] += t2;
        __syncthreads();
    }
    int beg = (b > 0) ? s[b - 1] : 0;      // CSR start of bucket b
    int ecnt = s[b] - beg;                 // edges in bucket b
    __syncthreads();
    cnt[t] = 0;
    cur[t] = 0;
    __syncthreads();
    const uint* eb = ebuf + (size_t)b * BCAP;
    for (int i = t; i < ecnt; i += 256)
        atomicAdd(&cnt[(eb[i] >> 16) & 255], 1);
    __syncthreads();
    int d = cnt[t];
    s[t] = d;
    __syncthreads();
    for (int off = 1; off < 256; off <<= 1) {
        int t2 = 0;
        if (t >= off) t2 = s[t - off];
        __syncthreads();
        s[t] += t2;
        __syncthreads();
    }
    exc[t] = s[t] - d;
    int node = b * 256 + t;
    if (node < N_NODES) {
        deg[node] = d;
        dinv[node] = rsqrtf((float)(d + 1));   // +1 self-loop
        rowptr[node] = beg + exc[t];
    }
    __syncthreads();
    for (int i = t; i < ecnt; i += 256) {
        uint u = eb[i];
        int dl = (int)(u >> 16) & 255;
        int pos = beg + exc[dl] + atomicAdd(&cur[dl], 1);
        esrc[pos] = (int)(u & 0xffffu);
    }
}

// ---------------- GEMM1: h1h[N,128] = f16(x[N,256]) @ W1  (MFMA f16, no LDS) ----------------
// Each lane loads its own A-frag: row w*16 + (lane&15), k = kt*32 + (lane>>4)*8 .. +8.
// packed cvt_pkrtz fp32->f16 (2/op). Rows clamped to avoid OOB; garbage rows discarded at store.

__global__ __launch_bounds__(256) void gemm1_mfma(const float* __restrict__ x,
                                                  const ushort* __restrict__ Bp,
                                                  ushort* __restrict__ h1h) {
    int t = threadIdx.x;
    int lane = t & 63, w = t >> 6;
    int r = lane & 15, q = lane >> 4;
    int row0 = blockIdx.x * 64;
    int arow = row0 + w * 16 + r;
    if (arow >= N_NODES) arow = N_NODES - 1;     // clamp: no fault, row discarded later
    const float* xrow = x + (size_t)arow * N_FEAT;
    f32x4 acc[8] = {};
    for (int kt = 0; kt < 8; ++kt) {
        float4 v0 = *(const float4*)(xrow + kt * 32 + q * 8);
        float4 v1 = *(const float4*)(xrow + kt * 32 + q * 8 + 4);
        union { fp16x2 p[4]; half8 a; } u;
        u.p[0] = __builtin_amdgcn_cvt_pkrtz(v0.x, v0.y);
        u.p[1] = __builtin_amdgcn_cvt_pkrtz(v0.z, v0.w);
        u.p[2] = __builtin_amdgcn_cvt_pkrtz(v1.x, v1.y);
        u.p[3] = __builtin_amdgcn_cvt_pkrtz(v1.z, v1.w);
#pragma unroll
        for (int nt = 0; nt < 8; ++nt) {
            half8 b = *(const half8*)(Bp + (((nt * 8 + kt) * 64) + lane) * 8);
            acc[nt] = __builtin_amdgcn_mfma_f32_16x16x32_f16(u.a, b, acc[nt], 0, 0, 0);
        }
    }
#pragma unroll
    for (int nt = 0; nt < 8; ++nt) {
        int col = nt * 16 + r;
#pragma unroll
        for (int reg = 0; reg < 4; ++reg) {
            int row = row0 + w * 16 + q * 4 + reg;
            if (row < N_NODES) h1h[(size_t)row * HIDDEN + col] = f2h(acc[nt][reg]);
        }
    }
}

// ---------------- layer-1 aggregation: quarter-wave edges, uint4 loads, __hfma2 ----------------

__global__ __launch_bounds__(256) void agg1_g(
        const int* __restrict__ rowptr, const int* __restrict__ deg,
        const int* __restrict__ esrc, const float* __restrict__ dinv,
        const ushort* __restrict__ h1h, const float* __restrict__ b1,
        ushort* __restrict__ hagh) {
    int w = threadIdx.x >> 6, lane = threadIdx.x & 63;
    int v = blockIdx.x * 4 + w;              // grid 12500 -> v < 50000
    int q = lane >> 4, l = lane & 15;
    int beg = rowptr[v], d = deg[v];
    float dv = dinv[v];
    __half2 z = __float2half2_rn(0.f);
    __half2 c0 = z, c1 = z, c2 = z, c3 = z;  // chain A
    __half2 e0 = z, e1 = z, e2 = z, e3 = z;  // chain B
    if (q == 0) {                            // self-loop counted once
        uint4 hv = *(const uint4*)(h1h + (size_t)v * HIDDEN + l * 8);
        __half2 gs = __float2half2_rn(dv * dv);
        c0 = __hfma2(u2h2(hv.x), gs, c0);
        c1 = __hfma2(u2h2(hv.y), gs, c1);
        c2 = __hfma2(u2h2(hv.z), gs, c2);
        c3 = __hfma2(u2h2(hv.w), gs, c3);
    }
    int e_l = (lane < d) ? esrc[beg + lane] : 0;
    float w_l = (lane < d) ? dinv[e_l] : 0.f;   // 0 weight: invalid edges vanish
    int dm = min(d, 64);
    int i = 0;
    for (; i + 8 <= dm; i += 8) {            // 8 edges per iter, 2 loads in flight
        int s0 = __shfl(e_l, i + q, 64);
        int s1 = __shfl(e_l, i + 4 + q, 64);
        float g0 = __shfl(w_l, i + q, 64) * dv;
        float g1 = __shfl(w_l, i + 4 + q, 64) * dv;
        __half2 gh0 = __float2half2_rn(g0);
        __half2 gh1 = __float2half2_rn(g1);
        uint4 h0 = *(const uint4*)(h1h + (size_t)s0 * HIDDEN + l * 8);
        uint4 h1 = *(const uint4*)(h1h + (size_t)s1 * HIDDEN + l * 8);
        c0 = __hfma2(u2h2(h0.x), gh0, c0);
        c1 = __hfma2(u2h2(h0.y), gh0, c1);
        c2 = __hfma2(u2h2(h0.z), gh0, c2);
        c3 = __hfma2(u2h2(h0.w), gh0, c3);
        e0 = __hfma2(u2h2(h1.x), gh1, e0);
        e1 = __hfma2(u2h2(h1.y), gh1, e1);
        e2 = __hfma2(u2h2(h1.z), gh1, e2);
        e3 = __hfma2(u2h2(h1.w), gh1, e3);
    }
    for (; i < dm; i += 4) {                 // tail: clamp shfl idx, mask weight
        int idx = i + q;
        int cl = idx & 63;
        int s0 = __shfl(e_l, cl, 64);
        float g0 = __shfl(w_l, cl, 64) * dv;
        if (idx >= dm) g0 = 0.f;
        __half2 gh0 = __float2half2_rn(g0);
        uint4 h0 = *(const uint4*)(h1h + (size_t)s0 * HIDDEN + l * 8);
        c0 = __hfma2(u2h2(h0.x), gh0, c0);
        c1 = __hfma2(u2h2(h0.y), gh0, c1);
        c2 = __hfma2(u2h2(h0.z), gh0, c2);
        c3 = __hfma2(u2h2(h0.w), gh0, c3);
    }
    for (int j = 64 + q; j < d; j += 4) {    // rare deg>64 tail
        int s = esrc[beg + j];
        __half2 g = __float2half2_rn(dinv[s] * dv);
        uint4 hs = *(const uint4*)(h1h + (size_t)s * HIDDEN + l * 8);
        c0 = __hfma2(u2h2(hs.x), g, c0);
        c1 = __hfma2(u2h2(hs.y), g, c1);
        c2 = __hfma2(u2h2(hs.z), g, c2);
        c3 = __hfma2(u2h2(hs.w), g, c3);
    }
    // combine chains in fp32
    float2 f0 = __half22float2(c0), f1 = __half22float2(c1);
    float2 f2 = __half22float2(c2), f3 = __half22float2(c3);
    float2 g0 = __half22float2(e0), g1 = __half22float2(e1);
    float2 g2 = __half22float2(e2), g3 = __half22float2(e3);
    float a0 = f0.x + g0.x, a1 = f0.y + g0.y;
    float a2 = f1.x + g1.x, a3 = f1.y + g1.y;
    float a4 = f2.x + g2.x, a5 = f2.y + g2.y;
    float a6 = f3.x + g3.x, a7 = f3.y + g3.y;
    // fold quarters
    a0 += __shfl_xor(a0, 16, 64); a0 += __shfl_xor(a0, 32, 64);
    a1 += __shfl_xor(a1, 16, 64); a1 += __shfl_xor(a1, 32, 64);
    a2 += __shfl_xor(a2, 16, 64); a2 += __shfl_xor(a2, 32, 64);
    a3 += __shfl_xor(a3, 16, 64); a3 += __shfl_xor(a3, 32, 64);
    a4 += __shfl_xor(a4, 16, 64); a4 += __shfl_xor(a4, 32, 64);
    a5 += __shfl_xor(a5, 16, 64); a5 += __shfl_xor(a5, 32, 64);
    a6 += __shfl_xor(a6, 16, 64); a6 += __shfl_xor(a6, 32, 64);
    a7 += __shfl_xor(a7, 16, 64); a7 += __shfl_xor(a7, 32, 64);
    if (q == 0) {
        float4 bb0 = ((const float4*)b1)[l * 2];
        float4 bb1 = ((const float4*)b1)[l * 2 + 1];
        a0 += bb0.x; a1 += bb0.y; a2 += bb0.z; a3 += bb0.w;
        a4 += bb1.x; a5 += bb1.y; a6 += bb1.z; a7 += bb1.w;
        a0 = a0 > 0.f ? a0 : 0.f;  a1 = a1 > 0.f ? a1 : 0.f;
        a2 = a2 > 0.f ? a2 : 0.f;  a3 = a3 > 0.f ? a3 : 0.f;
        a4 = a4 > 0.f ? a4 : 0.f;  a5 = a5 > 0.f ? a5 : 0.f;
        a6 = a6 > 0.f ? a6 : 0.f;  a7 = a7 > 0.f ? a7 : 0.f;
        uint4 ov;
        ov.x = ((uint)f2h(a1) << 16) | (uint)f2h(a0);
        ov.y = ((uint)f2h(a3) << 16) | (uint)f2h(a2);
        ov.z = ((uint)f2h(a5) << 16) | (uint)f2h(a4);
        ov.w = ((uint)f2h(a7) << 16) | (uint)f2h(a6);
        *(uint4*)(hagh + (size_t)v * HIDDEN + l * 8) = ov;
    }
}

// ---------------- GEMM2: h2h[N,H2S] = hagh[N,128] @ W2  (MFMA f16, padded rows) ----------------

__global__ __launch_bounds__(256) void gemm2_mfma(const ushort* __restrict__ hagh,
                                                  const ushort* __restrict__ Bp,
                                                  ushort* __restrict__ h2h) {
    int t = threadIdx.x;
    int lane = t & 63, w = t >> 6;
    int r = lane & 15, q = lane >> 4;
    int row0 = blockIdx.x * 64;
    int arow = row0 + w * 16 + r;            // rows < ROWS_PAD, buffer padded
    f32x4 acc[3] = {};
    for (int kt = 0; kt < 4; ++kt) {
        half8 a = *(const half8*)(hagh + (size_t)arow * HIDDEN + kt * 32 + q * 8);
#pragma unroll
        for (int nt = 0; nt < 3; ++nt) {
            half8 b = *(const half8*)(Bp + (((nt * 4 + kt) * 64) + lane) * 8);
            acc[nt] = __builtin_amdgcn_mfma_f32_16x16x32_f16(a, b, acc[nt], 0, 0, 0);
        }
    }
#pragma unroll
    for (int nt = 0; nt < 3; ++nt) {
        int col = nt * 16 + r;
        if (col >= N_CLASSES) continue;
#pragma unroll
        for (int reg = 0; reg < 4; ++reg) {
            int row = row0 + w * 16 + q * 4 + reg;
            if (row < N_NODES) h2h[(size_t)row * H2S + col] = f2h(acc[nt][reg]);
        }
    }
}

// ---------------- layer-2 aggregation + bias + log_softmax (2 nodes/wave, __hfma2) ----------------

__global__ __launch_bounds__(256) void agg2_lsm(
        const int* __restrict__ rowptr, const int* __restrict__ deg,
        const int* __restrict__ esrc, const float* __restrict__ dinv,
        const ushort* __restrict__ h2h, const float* __restrict__ b2,
        float* __restrict__ out) {
    int t = threadIdx.x;
    int w = t >> 6, lane = t & 63;
    int half = lane >> 5, l = lane & 31;
    int v = blockIdx.x * 8 + w * 2 + half;   // grid 6250 -> v < 50000 always
    int beg = rowptr[v], d = deg[v];
    float dv = dinv[v];
    __half2 z = __float2half2_rn(0.f);
    __half2 cA = z, cB = z;
    {   // self-loop (l<20 meaningful; rest discarded)
        uint hv = *(const uint*)(h2h + (size_t)v * H2S + l * 2);
        cA = __hfma2(u2h2(hv), __float2half2_rn(dv * dv), cA);
    }
    int e_l = (l < d) ? esrc[beg + l] : 0;
    float w_l = (l < d) ? dinv[e_l] : 0.f;
    int dm = min(d, 32);
    int base = half * 32;
    int i = 0;
    for (; i + 4 <= dm; i += 4) {
        int s0 = __shfl(e_l, base + i + 0, 64);
        int s1 = __shfl(e_l, base + i + 1, 64);
        int s2 = __shfl(e_l, base + i + 2, 64);
        int s3 = __shfl(e_l, base + i + 3, 64);
        float g0 = __shfl(w_l, base + i + 0, 64) * dv;
        float g1 = __shfl(w_l, base + i + 1, 64) * dv;
        float g2 = __shfl(w_l, base + i + 2, 64) * dv;
        float g3 = __shfl(w_l, base + i + 3, 64) * dv;
        uint h0 = *(const uint*)(h2h + (size_t)s0 * H2S + l * 2);
        uint h1 = *(const uint*)(h2h + (size_t)s1 * H2S + l * 2);
        uint h2 = *(const uint*)(h2h + (size_t)s2 * H2S + l * 2);
        uint h3 = *(const uint*)(h2h + (size_t)s3 * H2S + l * 2);
        cA = __hfma2(u2h2(h0), __float2half2_rn(g0), cA);
        cB = __hfma2(u2h2(h1), __float2half2_rn(g1), cB);
        cA = __hfma2(u2h2(h2), __float2half2_rn(g2), cA);
        cB = __hfma2(u2h2(h3), __float2half2_rn(g3), cB);
    }
    for (; i < dm; ++i) {
        int s0 = __shfl(e_l, base + i, 64);
        float g0 = __shfl(w_l, base + i, 64) * dv;
        uint h0 = *(const uint*)(h2h + (size_t)s0 * H2S + l * 2);
        cA = __hfma2(u2h2(h0), __float2half2_rn(g0), cA);
    }
    for (i = 32; i < d; ++i) {               // rare deg>32 tail
        int s = esrc[beg + i];
        float g = dinv[s] * dv;
        uint hs = *(const uint*)(h2h + (size_t)s * H2S + l * 2);
        cA = __hfma2(u2h2(hs), __float2half2_rn(g), cA);
    }
    float2 fA = __half22float2(cA);
    float2 fB = __half22float2(cB);
    float ax = fA.x + fB.x, ay = fA.y + fB.y;
    if (l < 20) {
        float2 bb = ((const float2*)b2)[l];
        ax += bb.x; ay += bb.y;
    }
    float m = (l < 20) ? fmaxf(ax, ay) : -INFINITY;
#pragma unroll
    for (int off = 16; off; off >>= 1) m = fmaxf(m, __shfl_xor(m, off, 64));
    float e = (l < 20) ? (expf(ax - m) + expf(ay - m)) : 0.f;
#pragma unroll
    for (int off = 16; off; off >>= 1) e += __shfl_xor(e, off, 64);
    float ls = logf(e);
    if (l < 20) {
        float2 o;
        o.x = ax - m - ls;
        o.y = ay - m - ls;
        ((float2*)(out + (size_t)v * N_CLASSES))[l] = o;
    }
}

// ---------------- launch ----------------

extern "C" void kernel_launch(void* const* d_in, const int* in_sizes, int n_in,
                              void* d_out, int out_size, void* d_ws, size_t ws_size,
                              hipStream_t stream) {
    const float* x  = (const float*)d_in[0];
    const int*   ei = (const int*)d_in[1];
    const float* W1 = (const float*)d_in[2];
    const float* b1 = (const float*)d_in[3];
    const float* W2 = (const float*)d_in[4];
    const float* b2 = (const float*)d_in[5];
    const int* src = ei;
    const int* dst = ei + N_EDGES;
    float* out = (float*)d_out;

    char* ws = (char*)d_ws;
    size_t off = 0;
    auto alloc = [&](size_t bytes) {
        void* p = ws + off;
        off += (bytes + 255) & ~(size_t)255;
        return p;
    };
    int*    cursor = (int*)alloc((size_t)NBUCKET * 4);
    int*    deg    = (int*)alloc((size_t)N_NODES * 4);
    float*  dinv   = (float*)alloc((size_t)N_NODES * 4);
    int*    rowptr = (int*)alloc((size_t)N_NODES * 4);
    uint*   ebuf   = (uint*)alloc((size_t)NBUCKET * BCAP * 4);
    int*    esrc   = (int*)alloc((size_t)N_EDGES * 4);
    ushort* Bp1    = (ushort*)alloc((size_t)32768 * 2);
    ushort* Bp2    = (ushort*)alloc((size_t)6144 * 2);
    ushort* h1h    = (ushort*)alloc((size_t)ROWS_PAD * HIDDEN * 2);
    ushort* hagh   = (ushort*)alloc((size_t)ROWS_PAD * HIDDEN * 2);
    ushort* h2h    = (ushort*)alloc((size_t)ROWS_PAD * H2S * 2);

    // --- preprocessing: tiny memset + 2 kernels ---
    (void)hipMemsetAsync(cursor, 0, (size_t)NBUCKET * 4, stream);
    partition_repack<<<256, 256, 0, stream>>>(src, dst, cursor, ebuf, W1, Bp1, W2, Bp2);
    bucket_csr<<<NBUCKET, 256, 0, stream>>>(ebuf, cursor, deg, dinv, rowptr, esrc);

    // --- model: 4 kernels ---
    gemm1_mfma<<<ROWS_PAD / 64, 256, 0, stream>>>(x, Bp1, h1h);
    agg1_g<<<N_NODES / 4, 256, 0, stream>>>(rowptr, deg, esrc, dinv, h1h, b1, hagh);
    gemm2_mfma<<<ROWS_PAD / 64, 256, 0, stream>>>(hagh, Bp2, h2h);
    agg2_lsm<<<N_NODES / 8, 256, 0, stream>>>(rowptr, deg, esrc, dinv, h2h, b2, out);
}

// Round 13
// 198.608 us; speedup vs baseline: 1.0032x; 1.0032x over previous
//
#include <hip/hip_runtime.h>
#include <hip/hip_fp16.h>
#include <cstdint>

#define N_NODES 50000
#define N_EDGES 800000
#define N_FEAT 256
#define HIDDEN 128
#define N_CLASSES 40
#define NBUCKET 196         // dst >> 8
#define EPB 3125            // edges per partition block (256 * 3125 = 800000)
#define BCAP 8192           // bucket capacity in ebuf (max count ~4400)
#define ROWS_PAD 50048      // 782 * 64
#define H2S 64              // h2 row stride (halves) = 128 B aligned

typedef _Float16 half8 __attribute__((ext_vector_type(8)));
typedef __fp16 fp16x2 __attribute__((ext_vector_type(2)));
typedef __attribute__((ext_vector_type(4))) float f32x4;

__device__ inline ushort f2h(float f) {
    return __half_as_ushort(__float2half_rn(f));
}
__device__ inline __half2 u2h2(uint u) {
    union { uint u; __half2 h; } v; v.u = u; return v.h;
}
__device__ inline uint h22u(__half2 h) {
    union { __half2 h; uint u; } v; v.h = h; return v.u;
}

// ---------------- 1) partition edges into fixed-capacity buckets + W1/W2 repack ----------------
// cursor[196] pre-zeroed by hipMemsetAsync; ends holding per-bucket edge counts.

__global__ __launch_bounds__(256) void partition_repack(
        const int* __restrict__ src, const int* __restrict__ dst,
        int* __restrict__ cursor, uint* __restrict__ ebuf,
        const float* __restrict__ W1, ushort* __restrict__ Bp1,
        const float* __restrict__ W2, ushort* __restrict__ Bp2) {
    __shared__ int h[NBUCKET];
    __shared__ int base[NBUCKET];
    __shared__ int cur[NBUCKET];
    int blk = blockIdx.x, t = threadIdx.x;
    int gid = blk * 256 + t;
    if (gid < 32768) {       // W1 repack into MFMA B-frag order (f16)
        int j = gid & 7, lane = (gid >> 3) & 63, kt = (gid >> 9) & 7, nt = gid >> 12;
        int k = kt * 32 + (lane >> 4) * 8 + j;
        int n = nt * 16 + (lane & 15);
        Bp1[gid] = f2h(W1[k * HIDDEN + n]);
    } else if (gid < 32768 + 6144) {   // W2 repack (3 nt * 4 kt * 64 * 8)
        int i2 = gid - 32768;
        int j = i2 & 7, lane = (i2 >> 3) & 63, kt = (i2 >> 9) & 3, nt = i2 >> 11;
        int k = kt * 32 + (lane >> 4) * 8 + j;
        int n = nt * 16 + (lane & 15);
        Bp2[i2] = (n < N_CLASSES) ? f2h(W2[k * N_CLASSES + n]) : (ushort)0;
    }
    if (t < NBUCKET) { h[t] = 0; cur[t] = 0; }
    __syncthreads();
    int eb = blk * EPB;
    for (int i = t; i < EPB; i += 256)
        atomicAdd(&h[dst[eb + i] >> 8], 1);
    __syncthreads();
    if (t < NBUCKET)
        base[t] = (h[t] > 0) ? atomicAdd(&cursor[t], h[t]) : 0;
    __syncthreads();
    for (int i = t; i < EPB; i += 256) {
        int d = dst[eb + i], sv = src[eb + i];
        int bk = d >> 8;
        int p = base[bk] + atomicAdd(&cur[bk], 1);
        ebuf[bk * BCAP + p] = ((uint)d << 16) | (uint)sv;
    }
}

// ---------------- 2) per-bucket: degree + dinv + rowptr + CSR fill ----------------

__global__ __launch_bounds__(256) void bucket_csr(
        const uint* __restrict__ ebuf, const int* __restrict__ cursor,
        int* __restrict__ deg, float* __restrict__ dinv,
        int* __restrict__ rowptr, int* __restrict__ esrc) {
    __shared__ int s[256];
    __shared__ int cnt[256];
    __shared__ int exc[256];
    __shared__ int cur[256];
    int b = blockIdx.x, t = threadIdx.x;
    s[t] = (t < NBUCKET) ? cursor[t] : 0;
    __syncthreads();
    for (int off = 1; off < 256; off <<= 1) {
        int t2 = 0;
        if (t >= off) t2 = s[t - off];
        __syncthreads();
        s[t] += t2;
        __syncthreads();
    }
    int beg = (b > 0) ? s[b - 1] : 0;      // CSR start of bucket b
    int ecnt = s[b] - beg;                 // edges in bucket b
    __syncthreads();
    cnt[t] = 0;
    cur[t] = 0;
    __syncthreads();
    const uint* eb = ebuf + (size_t)b * BCAP;
    for (int i = t; i < ecnt; i += 256)
        atomicAdd(&cnt[(eb[i] >> 16) & 255], 1);
    __syncthreads();
    int d = cnt[t];
    s[t] = d;
    __syncthreads();
    for (int off = 1; off < 256; off <<= 1) {
        int t2 = 0;
        if (t >= off) t2 = s[t - off];
        __syncthreads();
        s[t] += t2;
        __syncthreads();
    }
    exc[t] = s[t] - d;
    int node = b * 256 + t;
    if (node < N_NODES) {
        deg[node] = d;
        dinv[node] = rsqrtf((float)(d + 1));   // +1 self-loop
        rowptr[node] = beg + exc[t];
    }
    __syncthreads();
    for (int i = t; i < ecnt; i += 256) {
        uint u = eb[i];
        int dl = (int)(u >> 16) & 255;
        int pos = beg + exc[dl] + atomicAdd(&cur[dl], 1);
        esrc[pos] = (int)(u & 0xffffu);
    }
}

// ---------------- GEMM1: h1h[N,128] = f16(x[N,256]) @ W1  (MFMA f16, no LDS) ----------------

__global__ __launch_bounds__(256) void gemm1_mfma(const float* __restrict__ x,
                                                  const ushort* __restrict__ Bp,
                                                  ushort* __restrict__ h1h) {
    int t = threadIdx.x;
    int lane = t & 63, w = t >> 6;
    int r = lane & 15, q = lane >> 4;
    int row0 = blockIdx.x * 64;
    int arow = row0 + w * 16 + r;
    if (arow >= N_NODES) arow = N_NODES - 1;     // clamp: no fault, row discarded later
    const float* xrow = x + (size_t)arow * N_FEAT;
    f32x4 acc[8] = {};
    for (int kt = 0; kt < 8; ++kt) {
        float4 v0 = *(const float4*)(xrow + kt * 32 + q * 8);
        float4 v1 = *(const float4*)(xrow + kt * 32 + q * 8 + 4);
        union { fp16x2 p[4]; half8 a; } u;
        u.p[0] = __builtin_amdgcn_cvt_pkrtz(v0.x, v0.y);
        u.p[1] = __builtin_amdgcn_cvt_pkrtz(v0.z, v0.w);
        u.p[2] = __builtin_amdgcn_cvt_pkrtz(v1.x, v1.y);
        u.p[3] = __builtin_amdgcn_cvt_pkrtz(v1.z, v1.w);
#pragma unroll
        for (int nt = 0; nt < 8; ++nt) {
            half8 b = *(const half8*)(Bp + (((nt * 8 + kt) * 64) + lane) * 8);
            acc[nt] = __builtin_amdgcn_mfma_f32_16x16x32_f16(u.a, b, acc[nt], 0, 0, 0);
        }
    }
#pragma unroll
    for (int nt = 0; nt < 8; ++nt) {
        int col = nt * 16 + r;
#pragma unroll
        for (int reg = 0; reg < 4; ++reg) {
            int row = row0 + w * 16 + q * 4 + reg;
            if (row < N_NODES) h1h[(size_t)row * HIDDEN + col] = f2h(acc[nt][reg]);
        }
    }
}

// ---------------- layer-1 aggregation: quarter-wave edges, uint4 loads, __hfma2 ----------------
// Weight pre-packed as __half2 bits in the prologue -> 1 shfl + 0 cvt per edge.

__global__ __launch_bounds__(256) void agg1_g(
        const int* __restrict__ rowptr, const int* __restrict__ deg,
        const int* __restrict__ esrc, const float* __restrict__ dinv,
        const ushort* __restrict__ h1h, const float* __restrict__ b1,
        ushort* __restrict__ hagh) {
    int w = threadIdx.x >> 6, lane = threadIdx.x & 63;
    int v = blockIdx.x * 4 + w;              // grid 12500 -> v < 50000
    int q = lane >> 4, l = lane & 15;
    int beg = rowptr[v], d = deg[v];
    float dv = dinv[v];
    __half2 z = __float2half2_rn(0.f);
    __half2 c0 = z, c1 = z, c2 = z, c3 = z;  // chain A
    __half2 e0 = z, e1 = z, e2 = z, e3 = z;  // chain B
    if (q == 0) {                            // self-loop counted once
        uint4 hv = *(const uint4*)(h1h + (size_t)v * HIDDEN + l * 8);
        __half2 gs = __float2half2_rn(dv * dv);
        c0 = __hfma2(u2h2(hv.x), gs, c0);
        c1 = __hfma2(u2h2(hv.y), gs, c1);
        c2 = __hfma2(u2h2(hv.z), gs, c2);
        c3 = __hfma2(u2h2(hv.w), gs, c3);
    }
    int e_l = (lane < d) ? esrc[beg + lane] : 0;
    float wd = (lane < d) ? dinv[e_l] * dv : 0.f;   // 0: invalid edges vanish
    int whb = (int)h22u(__float2half2_rn(wd));      // packed half2 weight bits
    int dm = min(d, 64);
    int i = 0;
    for (; i + 16 <= dm; i += 16) {          // 16 edges per iter, 4 loads in flight
        int s0 = __shfl(e_l, i + q, 64);
        int s1 = __shfl(e_l, i + 4 + q, 64);
        int s2 = __shfl(e_l, i + 8 + q, 64);
        int s3 = __shfl(e_l, i + 12 + q, 64);
        __half2 gh0 = u2h2((uint)__shfl(whb, i + q, 64));
        __half2 gh1 = u2h2((uint)__shfl(whb, i + 4 + q, 64));
        __half2 gh2 = u2h2((uint)__shfl(whb, i + 8 + q, 64));
        __half2 gh3 = u2h2((uint)__shfl(whb, i + 12 + q, 64));
        uint4 h0 = *(const uint4*)(h1h + (size_t)s0 * HIDDEN + l * 8);
        uint4 h1 = *(const uint4*)(h1h + (size_t)s1 * HIDDEN + l * 8);
        uint4 h2 = *(const uint4*)(h1h + (size_t)s2 * HIDDEN + l * 8);
        uint4 h3 = *(const uint4*)(h1h + (size_t)s3 * HIDDEN + l * 8);
        c0 = __hfma2(u2h2(h0.x), gh0, c0);
        c1 = __hfma2(u2h2(h0.y), gh0, c1);
        c2 = __hfma2(u2h2(h0.z), gh0, c2);
        c3 = __hfma2(u2h2(h0.w), gh0, c3);
        e0 = __hfma2(u2h2(h1.x), gh1, e0);
        e1 = __hfma2(u2h2(h1.y), gh1, e1);
        e2 = __hfma2(u2h2(h1.z), gh1, e2);
        e3 = __hfma2(u2h2(h1.w), gh1, e3);
        c0 = __hfma2(u2h2(h2.x), gh2, c0);
        c1 = __hfma2(u2h2(h2.y), gh2, c1);
        c2 = __hfma2(u2h2(h2.z), gh2, c2);
        c3 = __hfma2(u2h2(h2.w), gh2, c3);
        e0 = __hfma2(u2h2(h3.x), gh3, e0);
        e1 = __hfma2(u2h2(h3.y), gh3, e1);
        e2 = __hfma2(u2h2(h3.z), gh3, e2);
        e3 = __hfma2(u2h2(h3.w), gh3, e3);
    }
    for (; i + 8 <= dm; i += 8) {            // 8 edges per iter
        int s0 = __shfl(e_l, i + q, 64);
        int s1 = __shfl(e_l, i + 4 + q, 64);
        __half2 gh0 = u2h2((uint)__shfl(whb, i + q, 64));
        __half2 gh1 = u2h2((uint)__shfl(whb, i + 4 + q, 64));
        uint4 h0 = *(const uint4*)(h1h + (size_t)s0 * HIDDEN + l * 8);
        uint4 h1 = *(const uint4*)(h1h + (size_t)s1 * HIDDEN + l * 8);
        c0 = __hfma2(u2h2(h0.x), gh0, c0);
        c1 = __hfma2(u2h2(h0.y), gh0, c1);
        c2 = __hfma2(u2h2(h0.z), gh0, c2);
        c3 = __hfma2(u2h2(h0.w), gh0, c3);
        e0 = __hfma2(u2h2(h1.x), gh1, e0);
        e1 = __hfma2(u2h2(h1.y), gh1, e1);
        e2 = __hfma2(u2h2(h1.z), gh1, e2);
        e3 = __hfma2(u2h2(h1.w), gh1, e3);
    }
    for (; i < dm; i += 4) {                 // tail: clamp shfl idx, mask weight
        int idx = i + q;
        int cl = idx & 63;
        int s0 = __shfl(e_l, cl, 64);
        __half2 gh0 = u2h2((uint)__shfl(whb, cl, 64));
        if (idx >= dm) gh0 = z;
        uint4 h0 = *(const uint4*)(h1h + (size_t)s0 * HIDDEN + l * 8);
        c0 = __hfma2(u2h2(h0.x), gh0, c0);
        c1 = __hfma2(u2h2(h0.y), gh0, c1);
        c2 = __hfma2(u2h2(h0.z), gh0, c2);
        c3 = __hfma2(u2h2(h0.w), gh0, c3);
    }
    for (int j = 64 + q; j < d; j += 4) {    // rare deg>64 tail
        int s = esrc[beg + j];
        __half2 g = __float2half2_rn(dinv[s] * dv);
        uint4 hs = *(const uint4*)(h1h + (size_t)s * HIDDEN + l * 8);
        c0 = __hfma2(u2h2(hs.x), g, c0);
        c1 = __hfma2(u2h2(hs.y), g, c1);
        c2 = __hfma2(u2h2(hs.z), g, c2);
        c3 = __hfma2(u2h2(hs.w), g, c3);
    }
    // combine chains in fp32
    float2 f0 = __half22float2(c0), f1 = __half22float2(c1);
    float2 f2 = __half22float2(c2), f3 = __half22float2(c3);
    float2 g0 = __half22float2(e0), g1 = __half22float2(e1);
    float2 g2 = __half22float2(e2), g3 = __half22float2(e3);
    float a0 = f0.x + g0.x, a1 = f0.y + g0.y;
    float a2 = f1.x + g1.x, a3 = f1.y + g1.y;
    float a4 = f2.x + g2.x, a5 = f2.y + g2.y;
    float a6 = f3.x + g3.x, a7 = f3.y + g3.y;
    // fold quarters
    a0 += __shfl_xor(a0, 16, 64); a0 += __shfl_xor(a0, 32, 64);
    a1 += __shfl_xor(a1, 16, 64); a1 += __shfl_xor(a1, 32, 64);
    a2 += __shfl_xor(a2, 16, 64); a2 += __shfl_xor(a2, 32, 64);
    a3 += __shfl_xor(a3, 16, 64); a3 += __shfl_xor(a3, 32, 64);
    a4 += __shfl_xor(a4, 16, 64); a4 += __shfl_xor(a4, 32, 64);
    a5 += __shfl_xor(a5, 16, 64); a5 += __shfl_xor(a5, 32, 64);
    a6 += __shfl_xor(a6, 16, 64); a6 += __shfl_xor(a6, 32, 64);
    a7 += __shfl_xor(a7, 16, 64); a7 += __shfl_xor(a7, 32, 64);
    if (q == 0) {
        float4 bb0 = ((const float4*)b1)[l * 2];
        float4 bb1 = ((const float4*)b1)[l * 2 + 1];
        a0 += bb0.x; a1 += bb0.y; a2 += bb0.z; a3 += bb0.w;
        a4 += bb1.x; a5 += bb1.y; a6 += bb1.z; a7 += bb1.w;
        a0 = a0 > 0.f ? a0 : 0.f;  a1 = a1 > 0.f ? a1 : 0.f;
        a2 = a2 > 0.f ? a2 : 0.f;  a3 = a3 > 0.f ? a3 : 0.f;
        a4 = a4 > 0.f ? a4 : 0.f;  a5 = a5 > 0.f ? a5 : 0.f;
        a6 = a6 > 0.f ? a6 : 0.f;  a7 = a7 > 0.f ? a7 : 0.f;
        uint4 ov;
        ov.x = ((uint)f2h(a1) << 16) | (uint)f2h(a0);
        ov.y = ((uint)f2h(a3) << 16) | (uint)f2h(a2);
        ov.z = ((uint)f2h(a5) << 16) | (uint)f2h(a4);
        ov.w = ((uint)f2h(a7) << 16) | (uint)f2h(a6);
        *(uint4*)(hagh + (size_t)v * HIDDEN + l * 8) = ov;
    }
}

// ---------------- GEMM2: h2h[N,H2S] = hagh[N,128] @ W2  (MFMA f16, padded rows) ----------------

__global__ __launch_bounds__(256) void gemm2_mfma(const ushort* __restrict__ hagh,
                                                  const ushort* __restrict__ Bp,
                                                  ushort* __restrict__ h2h) {
    int t = threadIdx.x;
    int lane = t & 63, w = t >> 6;
    int r = lane & 15, q = lane >> 4;
    int row0 = blockIdx.x * 64;
    int arow = row0 + w * 16 + r;            // rows < ROWS_PAD, buffer padded
    f32x4 acc[3] = {};
    for (int kt = 0; kt < 4; ++kt) {
        half8 a = *(const half8*)(hagh + (size_t)arow * HIDDEN + kt * 32 + q * 8);
#pragma unroll
        for (int nt = 0; nt < 3; ++nt) {
            half8 b = *(const half8*)(Bp + (((nt * 4 + kt) * 64) + lane) * 8);
            acc[nt] = __builtin_amdgcn_mfma_f32_16x16x32_f16(a, b, acc[nt], 0, 0, 0);
        }
    }
#pragma unroll
    for (int nt = 0; nt < 3; ++nt) {
        int col = nt * 16 + r;
        if (col >= N_CLASSES) continue;
#pragma unroll
        for (int reg = 0; reg < 4; ++reg) {
            int row = row0 + w * 16 + q * 4 + reg;
            if (row < N_NODES) h2h[(size_t)row * H2S + col] = f2h(acc[nt][reg]);
        }
    }
}

// ---------------- layer-2 aggregation + bias + log_softmax (2 nodes/wave, __hfma2) ----------------

__global__ __launch_bounds__(256) void agg2_lsm(
        const int* __restrict__ rowptr, const int* __restrict__ deg,
        const int* __restrict__ esrc, const float* __restrict__ dinv,
        const ushort* __restrict__ h2h, const float* __restrict__ b2,
        float* __restrict__ out) {
    int t = threadIdx.x;
    int w = t >> 6, lane = t & 63;
    int half = lane >> 5, l = lane & 31;
    int v = blockIdx.x * 8 + w * 2 + half;   // grid 6250 -> v < 50000 always
    int beg = rowptr[v], d = deg[v];
    float dv = dinv[v];
    __half2 z = __float2half2_rn(0.f);
    __half2 cA = z, cB = z;
    {   // self-loop (l<20 meaningful; rest discarded)
        uint hv = *(const uint*)(h2h + (size_t)v * H2S + l * 2);
        cA = __hfma2(u2h2(hv), __float2half2_rn(dv * dv), cA);
    }
    int e_l = (l < d) ? esrc[beg + l] : 0;
    float wd = (l < d) ? dinv[e_l] * dv : 0.f;
    int whb = (int)h22u(__float2half2_rn(wd));
    int dm = min(d, 32);
    int base = half * 32;
    int i = 0;
    for (; i + 8 <= dm; i += 8) {            // 8 edges per iter, 8 loads in flight
        int s0 = __shfl(e_l, base + i + 0, 64);
        int s1 = __shfl(e_l, base + i + 1, 64);
        int s2 = __shfl(e_l, base + i + 2, 64);
        int s3 = __shfl(e_l, base + i + 3, 64);
        int s4 = __shfl(e_l, base + i + 4, 64);
        int s5 = __shfl(e_l, base + i + 5, 64);
        int s6 = __shfl(e_l, base + i + 6, 64);
        int s7 = __shfl(e_l, base + i + 7, 64);
        __half2 g0 = u2h2((uint)__shfl(whb, base + i + 0, 64));
        __half2 g1 = u2h2((uint)__shfl(whb, base + i + 1, 64));
        __half2 g2 = u2h2((uint)__shfl(whb, base + i + 2, 64));
        __half2 g3 = u2h2((uint)__shfl(whb, base + i + 3, 64));
        __half2 g4 = u2h2((uint)__shfl(whb, base + i + 4, 64));
        __half2 g5 = u2h2((uint)__shfl(whb, base + i + 5, 64));
        __half2 g6 = u2h2((uint)__shfl(whb, base + i + 6, 64));
        __half2 g7 = u2h2((uint)__shfl(whb, base + i + 7, 64));
        uint h0 = *(const uint*)(h2h + (size_t)s0 * H2S + l * 2);
        uint h1 = *(const uint*)(h2h + (size_t)s1 * H2S + l * 2);
        uint h2 = *(const uint*)(h2h + (size_t)s2 * H2S + l * 2);
        uint h3 = *(const uint*)(h2h + (size_t)s3 * H2S + l * 2);
        uint h4 = *(const uint*)(h2h + (size_t)s4 * H2S + l * 2);
        uint h5 = *(const uint*)(h2h + (size_t)s5 * H2S + l * 2);
        uint h6 = *(const uint*)(h2h + (size_t)s6 * H2S + l * 2);
        uint h7 = *(const uint*)(h2h + (size_t)s7 * H2S + l * 2);
        cA = __hfma2(u2h2(h0), g0, cA);
        cB = __hfma2(u2h2(h1), g1, cB);
        cA = __hfma2(u2h2(h2), g2, cA);
        cB = __hfma2(u2h2(h3), g3, cB);
        cA = __hfma2(u2h2(h4), g4, cA);
        cB = __hfma2(u2h2(h5), g5, cB);
        cA = __hfma2(u2h2(h6), g6, cA);
        cB = __hfma2(u2h2(h7), g7, cB);
    }
    for (; i + 4 <= dm; i += 4) {
        int s0 = __shfl(e_l, base + i + 0, 64);
        int s1 = __shfl(e_l, base + i + 1, 64);
        int s2 = __shfl(e_l, base + i + 2, 64);
        int s3 = __shfl(e_l, base + i + 3, 64);
        __half2 g0 = u2h2((uint)__shfl(whb, base + i + 0, 64));
        __half2 g1 = u2h2((uint)__shfl(whb, base + i + 1, 64));
        __half2 g2 = u2h2((uint)__shfl(whb, base + i + 2, 64));
        __half2 g3 = u2h2((uint)__shfl(whb, base + i + 3, 64));
        uint h0 = *(const uint*)(h2h + (size_t)s0 * H2S + l * 2);
        uint h1 = *(const uint*)(h2h + (size_t)s1 * H2S + l * 2);
        uint h2 = *(const uint*)(h2h + (size_t)s2 * H2S + l * 2);
        uint h3 = *(const uint*)(h2h + (size_t)s3 * H2S + l * 2);
        cA = __hfma2(u2h2(h0), g0, cA);
        cB = __hfma2(u2h2(h1), g1, cB);
        cA = __hfma2(u2h2(h2), g2, cA);
        cB = __hfma2(u2h2(h3), g3, cB);
    }
    for (; i < dm; ++i) {
        int s0 = __shfl(e_l, base + i, 64);
        __half2 g0 = u2h2((uint)__shfl(whb, base + i, 64));
        uint h0 = *(const uint*)(h2h + (size_t)s0 * H2S + l * 2);
        cA = __hfma2(u2h2(h0), g0, cA);
    }
    for (i = 32; i < d; ++i) {               // rare deg>32 tail
        int s = esrc[beg + i];
        float g = dinv[s] * dv;
        uint hs = *(const uint*)(h2h + (size_t)s * H2S + l * 2);
        cA = __hfma2(u2h2(hs), __float2half2_rn(g), cA);
    }
    float2 fA = __half22float2(cA);
    float2 fB = __half22float2(cB);
    float ax = fA.x + fB.x, ay = fA.y + fB.y;
    if (l < 20) {
        float2 bb = ((const float2*)b2)[l];
        ax += bb.x; ay += bb.y;
    }
    float m = (l < 20) ? fmaxf(ax, ay) : -INFINITY;
#pragma unroll
    for (int off = 16; off; off >>= 1) m = fmaxf(m, __shfl_xor(m, off, 64));
    float e = (l < 20) ? (expf(ax - m) + expf(ay - m)) : 0.f;
#pragma unroll
    for (int off = 16; off; off >>= 1) e += __shfl_xor(e, off, 64);
    float ls = logf(e);
    if (l < 20) {
        float2 o;
        o.x = ax - m - ls;
        o.y = ay - m - ls;
        ((float2*)(out + (size_t)v * N_CLASSES))[l] = o;
    }
}

// ---------------- launch ----------------

extern "C" void kernel_launch(void* const* d_in, const int* in_sizes, int n_in,
                              void* d_out, int out_size, void* d_ws, size_t ws_size,
                              hipStream_t stream) {
    const float* x  = (const float*)d_in[0];
    const int*   ei = (const int*)d_in[1];
    const float* W1 = (const float*)d_in[2];
    const float* b1 = (const float*)d_in[3];
    const float* W2 = (const float*)d_in[4];
    const float* b2 = (const float*)d_in[5];
    const int* src = ei;
    const int* dst = ei + N_EDGES;
    float* out = (float*)d_out;

    char* ws = (char*)d_ws;
    size_t off = 0;
    auto alloc = [&](size_t bytes) {
        void* p = ws + off;
        off += (bytes + 255) & ~(size_t)255;
        return p;
    };
    int*    cursor = (int*)alloc((size_t)NBUCKET * 4);
    int*    deg    = (int*)alloc((size_t)N_NODES * 4);
    float*  dinv   = (float*)alloc((size_t)N_NODES * 4);
    int*    rowptr = (int*)alloc((size_t)N_NODES * 4);
    uint*   ebuf   = (uint*)alloc((size_t)NBUCKET * BCAP * 4);
    int*    esrc   = (int*)alloc((size_t)N_EDGES * 4);
    ushort* Bp1    = (ushort*)alloc((size_t)32768 * 2);
    ushort* Bp2    = (ushort*)alloc((size_t)6144 * 2);
    ushort* h1h    = (ushort*)alloc((size_t)ROWS_PAD * HIDDEN * 2);
    ushort* hagh   = (ushort*)alloc((size_t)ROWS_PAD * HIDDEN * 2);
    ushort* h2h    = (ushort*)alloc((size_t)ROWS_PAD * H2S * 2);

    // --- preprocessing: tiny memset + 2 kernels ---
    (void)hipMemsetAsync(cursor, 0, (size_t)NBUCKET * 4, stream);
    partition_repack<<<256, 256, 0, stream>>>(src, dst, cursor, ebuf, W1, Bp1, W2, Bp2);
    bucket_csr<<<NBUCKET, 256, 0, stream>>>(ebuf, cursor, deg, dinv, rowptr, esrc);

    // --- model: 4 kernels ---
    gemm1_mfma<<<ROWS_PAD / 64, 256, 0, stream>>>(x, Bp1, h1h);
    agg1_g<<<N_NODES / 4, 256, 0, stream>>>(rowptr, deg, esrc, dinv, h1h, b1, hagh);
    gemm2_mfma<<<ROWS_PAD / 64, 256, 0, stream>>>(hagh, Bp2, h2h);
    agg2_lsm<<<N_NODES / 8, 256, 0, stream>>>(rowptr, deg, esrc, dinv, h2h, b2, out);
}